// Round 10
// baseline (44.545 us; speedup 1.0000x reference)
//
#include <hip/hip_runtime.h>
#include <hip/hip_bf16.h>

typedef unsigned short u16;
typedef unsigned int u32;
typedef __attribute__((ext_vector_type(8))) short bf16x8;
typedef __attribute__((ext_vector_type(4))) float f32x4;

__device__ __forceinline__ u16 f2bf(float f) {
  return __builtin_bit_cast(u16, __float2bfloat16(f));
}

__device__ __forceinline__ bf16x8 ld_frag16(const u16* p) {
  return __builtin_bit_cast(bf16x8, *reinterpret_cast<const uint4*>(p));
}

__device__ __forceinline__ void gload_lds16(const void* g, void* l) {
  __builtin_amdgcn_global_load_lds((const __attribute__((address_space(1))) void*)g,
                                   (__attribute__((address_space(3))) void*)l, 16, 0, 0);
}

// Barrier without vmcnt drain: publish LDS writes, fence scheduler, raw barrier.
__device__ __forceinline__ void bar_lds() {
  asm volatile("s_waitcnt lgkmcnt(0)" ::: "memory");
  __builtin_amdgcn_sched_barrier(0);
  __builtin_amdgcn_s_barrier();
}

// ---------------------------------------------------------------------------
// Kernel 1: Y[b] = bf16( W @ X[b] )   (unchanged)
// ---------------------------------------------------------------------------
__global__ __launch_bounds__(256, 3) void gemm1(
    const float* __restrict__ x, const float* __restrict__ weight,
    u16* __restrict__ Y)
{
  constexpr int Nn = 1024, K = 256, BK = 32, SB = 40;
  __shared__ __align__(16) u16 As[128 * 32];
  __shared__ __align__(16) u16 Bs[64 * SB];

  const int t = threadIdx.x;
  const int b = blockIdx.z, mt = blockIdx.y, n0 = blockIdx.x * 64;

  const float* Wp = weight + (size_t)mt * 128 * K;
  const float* Xb = x + (size_t)b * K * Nn;

  const int w = t >> 6, l = t & 63;
  const int wm = w >> 1, wn = w & 1;
  const int lr = l & 15, lg = l >> 4;

  const int ar = t >> 1, akc = (t & 1) * 16;
  const int bm = t & 63, bkq = t >> 6;
  const float* Xcol = Xb + n0 + bm;

  f32x4 acc[4][2] = {};

  for (int kt = 0; kt < K / BK; ++kt) {
    const int k0 = kt * BK;

    float4 a4[4];
#pragma unroll
    for (int uu = 0; uu < 4; ++uu)
      a4[uu] = reinterpret_cast<const float4*>(Wp + (size_t)ar * K + k0 + akc)[uu];
    union { uint4 q[2]; u16 s[16]; } ua;
#pragma unroll
    for (int uu = 0; uu < 4; ++uu) {
      ua.s[uu * 4 + 0] = f2bf(a4[uu].x); ua.s[uu * 4 + 1] = f2bf(a4[uu].y);
      ua.s[uu * 4 + 2] = f2bf(a4[uu].z); ua.s[uu * 4 + 3] = f2bf(a4[uu].w);
    }
    {
      const int c0 = akc >> 3;
      const int sw = (ar >> 1) & 3;
      uint4* Aq = reinterpret_cast<uint4*>(As);
      Aq[ar * 4 + ((c0 + 0) ^ sw)] = ua.q[0];
      Aq[ar * 4 + ((c0 + 1) ^ sw)] = ua.q[1];
    }

    float v[8];
#pragma unroll
    for (int j = 0; j < 8; ++j)
      v[j] = Xcol[(size_t)(k0 + bkq * 8 + j) * Nn];
    union { uint4 q; u16 s[8]; } ub;
#pragma unroll
    for (int j = 0; j < 8; ++j) ub.s[j] = f2bf(v[j]);
    reinterpret_cast<uint4*>(Bs)[bm * 5 + bkq] = ub.q;

    __syncthreads();

    bf16x8 af[4], bfr[2];
#pragma unroll
    for (int mi = 0; mi < 4; ++mi) {
      const int rr = wm * 64 + mi * 16 + lr;
      const int cw = lg ^ ((rr >> 1) & 3);
      af[mi] = ld_frag16(As + rr * BK + cw * 8);
    }
#pragma unroll
    for (int ni = 0; ni < 2; ++ni) {
      const int cc = wn * 32 + ni * 16 + lr;
      bfr[ni] = ld_frag16(Bs + cc * SB + lg * 8);
    }
#pragma unroll
    for (int mi = 0; mi < 4; ++mi)
#pragma unroll
      for (int ni = 0; ni < 2; ++ni)
        acc[mi][ni] = __builtin_amdgcn_mfma_f32_16x16x32_bf16(
            af[mi], bfr[ni], acc[mi][ni], 0, 0, 0);

    __syncthreads();
  }

#pragma unroll
  for (int mi = 0; mi < 4; ++mi) {
#pragma unroll
    for (int rr = 0; rr < 4; ++rr) {
      const int row = mt * 128 + wm * 64 + mi * 16 + lg * 4 + rr;
      u16* Yrow = Y + ((size_t)(b * 256 + row)) * Nn + n0;
#pragma unroll
      for (int ni = 0; ni < 2; ++ni) {
        const int col = wn * 32 + ni * 16 + lr;
        Yrow[col] = f2bf(acc[mi][ni][rr]);
      }
    }
  }
}

// ---------------------------------------------------------------------------
// Kernel 2 (v8 = v7 with 8-buffer A ring): out = relu(Y_half @ adj_h + bias)
// BM=128, BN=128, BK=32. 256 blocks (XCD-clustered), 512 thr (8 waves).
// Unroll-4, 4 static B-register sets (B loaded 3 halves before use),
// A gloads at distance 3 on an 8-BUFFER ring (fixes v7's race: with 4
// buffers, write(tt+3) aliased COMPUTE(tt-1)'s buffer). Concurrent-live
// buffers {tt-1, tt, tt+1, tt+2, tt+3} are distinct mod 8.
// Completion proof: PASS1(tt+1) vmcnt-waits on B(tt+1), issued AFTER
// ISSUE_A(tt) in half tt-3 => in-order vmcnt ⇒ A(tt) landed before
// COMPUTE(tt). Final tiles: explicit vmcnt(0).
// ---------------------------------------------------------------------------
__global__ __launch_bounds__(512, 1) void gemm2(
    const float* __restrict__ adj1, const float* __restrict__ adj2,
    const u16* __restrict__ Y, const float* __restrict__ bias,
    float* __restrict__ out)
{
  constexpr int Nn = 1024, BK = 32, NT = Nn / BK;
  constexpr int SB1 = 132;   // Bb row stride (elems): 128 + 4 pad
  constexpr int SB2 = 40;    // Bs2 row stride (elems)
  __shared__ __align__(16) u16 As[8][128 * 32];     // 8 x 8 KB = 64 KB
  __shared__ __align__(16) u16 Bb[2][32 * SB1];     // 2 x 8.25 KB  [k][n] bf16
  __shared__ __align__(16) u16 Bs2[2][128 * SB2];   // 2 x 10 KB    [n][k] bf16

  const int t = threadIdx.x;

  // XCD-clustered decode: pair p's 8 n-tile blocks all share bid%8.
  const int bid = blockIdx.x;
  const int xcd = bid & 7;
  const int nt  = (bid >> 3) & 7;
  const int pg  = bid >> 6;
  const int p   = xcd + pg * 8;    // 0..31
  const int b   = p >> 1, h = p & 1;
  const int n0  = nt * 128;

  const float* adj = (h == 0 ? adj1 : adj2) + (size_t)b * Nn * Nn;
  const u16* Yb = Y + ((size_t)(b * 256 + h * 128)) * Nn;  // [128][1024] bf16

  const int w = t >> 6, l = t & 63;
  const int wm = w >> 2, wn = w & 3;          // 2 m x 4 n waves
  const int lr = l & 15, lg = l >> 4;

  // ---- A staging: chunk t of 512, source-swizzled ----
  const int a_r = t >> 2, a_c = t & 3;
  const int a_cg = a_c ^ ((a_r >> 1) & 3);
  const u16* a_src = Yb + (size_t)a_r * Nn + a_cg * 8;   // + tt*BK at use
  const int a_dstoff = (w * 64) * 8;                      // u16 elements

  // ---- B pass1: row-wise contiguous reads ----
  const int b1r = t >> 5, b1c4 = t & 31;
  const float* bsrc0 = adj + (size_t)(0 * 16 + b1r) * Nn + n0 + 4 * b1c4;
  const float* bsrc1 = adj + (size_t)(1 * 16 + b1r) * Nn + n0 + 4 * b1c4;

  // ---- B pass2: thread owns col n = t>>2, k-quad kq = t&3 ----
  const int p2n = t >> 2, p2kq = t & 3;

  f32x4 acc[4][2] = {};

  auto ISSUE_A = [&](int tt) {
    gload_lds16(a_src + tt * BK, (void*)(&As[tt & 7][0] + a_dstoff));
  };
  auto LOAD_B = [&](int tt, float4 (&v)[2]) {
    v[0] = *reinterpret_cast<const float4*>(bsrc0 + (size_t)tt * BK * Nn);
    v[1] = *reinterpret_cast<const float4*>(bsrc1 + (size_t)tt * BK * Nn);
  };
  auto PASS1 = [&](int tt, const float4 (&v)[2]) {
#pragma unroll
    for (int i = 0; i < 2; ++i) {
      union { uint2 q; u16 s[4]; } ub;
      ub.s[0] = f2bf(v[i].x); ub.s[1] = f2bf(v[i].y);
      ub.s[2] = f2bf(v[i].z); ub.s[3] = f2bf(v[i].w);
      *reinterpret_cast<uint2*>(&Bb[tt & 1][0] + (i * 16 + b1r) * SB1 + 4 * b1c4) = ub.q;
    }
  };
  auto PASS2 = [&](int tt) {
    const u16* src = &Bb[tt & 1][0];
    union { uint4 q; u16 s[8]; } up;
#pragma unroll
    for (int j2 = 0; j2 < 8; ++j2)
      up.s[j2] = src[(p2kq * 8 + j2) * SB1 + p2n];
    *reinterpret_cast<uint4*>(&Bs2[tt & 1][0] + p2n * SB2 + p2kq * 8) = up.q;
  };
  auto COMPUTE = [&](int tt) {
    const u16* Ab = &As[tt & 7][0];
    const u16* Bbf = &Bs2[tt & 1][0];
    bf16x8 af[4], bfr[2];
#pragma unroll
    for (int mi = 0; mi < 4; ++mi) {
      const int rr = wm * 64 + mi * 16 + lr;
      const int cw = lg ^ ((rr >> 1) & 3);
      af[mi] = ld_frag16(Ab + rr * BK + cw * 8);
    }
#pragma unroll
    for (int ni = 0; ni < 2; ++ni) {
      const int cc = wn * 32 + ni * 16 + lr;
      bfr[ni] = ld_frag16(Bbf + cc * SB2 + lg * 8);
    }
#pragma unroll
    for (int mi = 0; mi < 4; ++mi)
#pragma unroll
      for (int ni = 0; ni < 2; ++ni)
        acc[mi][ni] = __builtin_amdgcn_mfma_f32_16x16x32_bf16(
            af[mi], bfr[ni], acc[mi][ni], 0, 0, 0);
  };

  // 4 static register sets: tile t -> set t&3 (never runtime-indexed).
  float4 s0[2], s1[2], s2[2], s3[2];

  // One half-iteration at tile t: loads set `ld` (tile t+4), PASS1 consumes
  // set `ps` (tile t+1, loaded 3 halves ago).
  auto HALF = [&](int tt, float4 (&ld)[2], float4 (&ps)[2]) {
    if (tt + 3 < NT) ISSUE_A(tt + 3);
    if (tt + 4 < NT) LOAD_B(tt + 4, ld);
    if (tt + 1 < NT) PASS1(tt + 1, ps);
    else asm volatile("s_waitcnt vmcnt(0)" ::: "memory");  // drain A(31)
    PASS2(tt);
    bar_lds();
    COMPUTE(tt);
  };

  // ---- prologue: A(0..2) and B(0..3) in flight; Bb[0] published ----
  ISSUE_A(0); LOAD_B(0, s0);
  ISSUE_A(1); LOAD_B(1, s1);
  ISSUE_A(2); LOAD_B(2, s2);
  LOAD_B(3, s3);
  PASS1(0, s0);              // vmcnt wait proves A(0) also landed
  bar_lds();

  // ---- main loop: 8 iterations x 4 tiles ----
  for (int i = 0; i < NT / 4; ++i) {
    const int t0 = 4 * i;
    HALF(t0 + 0, s0, s1);
    HALF(t0 + 1, s1, s2);
    HALF(t0 + 2, s2, s3);
    HALF(t0 + 3, s3, s0);
  }

  // ---- epilogue: bias + relu, fp32 store ----
#pragma unroll
  for (int mi = 0; mi < 4; ++mi) {
#pragma unroll
    for (int rr = 0; rr < 4; ++rr) {
      const int go = h * 128 + wm * 64 + mi * 16 + lg * 4 + rr;
      const float bi = bias[go];
      float* orow = out + ((size_t)(b * 256 + go)) * Nn + n0;
#pragma unroll
      for (int ni = 0; ni < 2; ++ni) {
        const int col = wn * 32 + ni * 16 + lr;
        orow[col] = fmaxf(acc[mi][ni][rr] + bi, 0.f);
      }
    }
  }
}

extern "C" void kernel_launch(void* const* d_in, const int* in_sizes, int n_in,
                              void* d_out, int out_size, void* d_ws, size_t ws_size,
                              hipStream_t stream) {
  const float* x    = (const float*)d_in[0];
  const float* adj1 = (const float*)d_in[1];
  const float* adj2 = (const float*)d_in[2];
  const float* wgt  = (const float*)d_in[3];
  const float* bias = (const float*)d_in[4];
  float* out = (float*)d_out;
  u16* Y = (u16*)d_ws;   // 16*256*1024 bf16 = 8.4 MB

  dim3 g1(16, 2, 16);
  gemm1<<<g1, dim3(256), 0, stream>>>(x, wgt, Y);
  gemm2<<<dim3(256), dim3(512), 0, stream>>>(adj1, adj2, Y, bias, out);
}

// Round 11
// 44.030 us; speedup vs baseline: 1.0117x; 1.0117x over previous
//
#include <hip/hip_runtime.h>
#include <hip/hip_bf16.h>

typedef unsigned short u16;
typedef unsigned int u32;
typedef __attribute__((ext_vector_type(8))) short bf16x8;
typedef __attribute__((ext_vector_type(4))) float f32x4;

__device__ __forceinline__ u16 f2bf(float f) {
  return __builtin_bit_cast(u16, __float2bfloat16(f));
}

__device__ __forceinline__ bf16x8 ld_frag16(const u16* p) {
  return __builtin_bit_cast(bf16x8, *reinterpret_cast<const uint4*>(p));
}

__device__ __forceinline__ void gload_lds16(const void* g, void* l) {
  __builtin_amdgcn_global_load_lds((const __attribute__((address_space(1))) void*)g,
                                   (__attribute__((address_space(3))) void*)l, 16, 0, 0);
}

// Barrier without vmcnt drain: publish LDS writes, fence scheduler, raw barrier.
__device__ __forceinline__ void bar_lds() {
  asm volatile("s_waitcnt lgkmcnt(0)" ::: "memory");
  __builtin_amdgcn_sched_barrier(0);
  __builtin_amdgcn_s_barrier();
}

// ---------------------------------------------------------------------------
// Kernel 1: Y[b] = bf16( W @ X[b] )   (unchanged)
// ---------------------------------------------------------------------------
__global__ __launch_bounds__(256, 3) void gemm1(
    const float* __restrict__ x, const float* __restrict__ weight,
    u16* __restrict__ Y)
{
  constexpr int Nn = 1024, K = 256, BK = 32, SB = 40;
  __shared__ __align__(16) u16 As[128 * 32];
  __shared__ __align__(16) u16 Bs[64 * SB];

  const int t = threadIdx.x;
  const int b = blockIdx.z, mt = blockIdx.y, n0 = blockIdx.x * 64;

  const float* Wp = weight + (size_t)mt * 128 * K;
  const float* Xb = x + (size_t)b * K * Nn;

  const int w = t >> 6, l = t & 63;
  const int wm = w >> 1, wn = w & 1;
  const int lr = l & 15, lg = l >> 4;

  const int ar = t >> 1, akc = (t & 1) * 16;
  const int bm = t & 63, bkq = t >> 6;
  const float* Xcol = Xb + n0 + bm;

  f32x4 acc[4][2] = {};

  for (int kt = 0; kt < K / BK; ++kt) {
    const int k0 = kt * BK;

    float4 a4[4];
#pragma unroll
    for (int uu = 0; uu < 4; ++uu)
      a4[uu] = reinterpret_cast<const float4*>(Wp + (size_t)ar * K + k0 + akc)[uu];
    union { uint4 q[2]; u16 s[16]; } ua;
#pragma unroll
    for (int uu = 0; uu < 4; ++uu) {
      ua.s[uu * 4 + 0] = f2bf(a4[uu].x); ua.s[uu * 4 + 1] = f2bf(a4[uu].y);
      ua.s[uu * 4 + 2] = f2bf(a4[uu].z); ua.s[uu * 4 + 3] = f2bf(a4[uu].w);
    }
    {
      const int c0 = akc >> 3;
      const int sw = (ar >> 1) & 3;
      uint4* Aq = reinterpret_cast<uint4*>(As);
      Aq[ar * 4 + ((c0 + 0) ^ sw)] = ua.q[0];
      Aq[ar * 4 + ((c0 + 1) ^ sw)] = ua.q[1];
    }

    float v[8];
#pragma unroll
    for (int j = 0; j < 8; ++j)
      v[j] = Xcol[(size_t)(k0 + bkq * 8 + j) * Nn];
    union { uint4 q; u16 s[8]; } ub;
#pragma unroll
    for (int j = 0; j < 8; ++j) ub.s[j] = f2bf(v[j]);
    reinterpret_cast<uint4*>(Bs)[bm * 5 + bkq] = ub.q;

    __syncthreads();

    bf16x8 af[4], bfr[2];
#pragma unroll
    for (int mi = 0; mi < 4; ++mi) {
      const int rr = wm * 64 + mi * 16 + lr;
      const int cw = lg ^ ((rr >> 1) & 3);
      af[mi] = ld_frag16(As + rr * BK + cw * 8);
    }
#pragma unroll
    for (int ni = 0; ni < 2; ++ni) {
      const int cc = wn * 32 + ni * 16 + lr;
      bfr[ni] = ld_frag16(Bs + cc * SB + lg * 8);
    }
#pragma unroll
    for (int mi = 0; mi < 4; ++mi)
#pragma unroll
      for (int ni = 0; ni < 2; ++ni)
        acc[mi][ni] = __builtin_amdgcn_mfma_f32_16x16x32_bf16(
            af[mi], bfr[ni], acc[mi][ni], 0, 0, 0);

    __syncthreads();
  }

#pragma unroll
  for (int mi = 0; mi < 4; ++mi) {
#pragma unroll
    for (int rr = 0; rr < 4; ++rr) {
      const int row = mt * 128 + wm * 64 + mi * 16 + lg * 4 + rr;
      u16* Yrow = Y + ((size_t)(b * 256 + row)) * Nn + n0;
#pragma unroll
      for (int ni = 0; ni < 2; ++ni) {
        const int col = wn * 32 + ni * 16 + lr;
        Yrow[col] = f2bf(acc[mi][ni][rr]);
      }
    }
  }
}

// ---------------------------------------------------------------------------
// Kernel 2 (v9 = v6 structure at 2 blocks/CU): out = relu(Y_half @ adj_h + b)
// BM=128, BN=64, BK=32. 512 blocks (XCD pair-clustered, 16 n-tiles/pair),
// 256 thr (4 waves, 2m x 2n; wave tile 64x32 — same COMPUTE as v6).
// v6 schedule: distance-2 globals, 4-buffer A ring, dbuf Bb/Bs2 two-pass
// B transpose, raw lgkm-barrier, counted vmcnt. LDS 51 KB -> 2 blocks/CU
// co-resident: partner block fills barrier/LDS drain gaps (m114 mechanism).
// ---------------------------------------------------------------------------
__global__ __launch_bounds__(256, 2) void gemm2(
    const float* __restrict__ adj1, const float* __restrict__ adj2,
    const u16* __restrict__ Y, const float* __restrict__ bias,
    float* __restrict__ out)
{
  constexpr int Nn = 1024, BK = 32, NT = Nn / BK;
  constexpr int SB1 = 68;    // Bb row stride (elems): 64 + 4 pad
  constexpr int SB2 = 40;    // Bs2 row stride (elems)
  __shared__ __align__(16) u16 As[4][128 * 32];    // 4 x 8 KB
  __shared__ __align__(16) u16 Bb[2][32 * SB1];    // 2 x 4.25 KB  [k][n] bf16
  __shared__ __align__(16) u16 Bs2[2][64 * SB2];   // 2 x 5 KB     [n][k] bf16

  const int t = threadIdx.x;

  // XCD-clustered decode: 512 = 8 xcd * 16 nt * 4 pg; pair p = pg*8 + xcd.
  const int bid = blockIdx.x;
  const int xcd = bid & 7;
  const int nt  = (bid >> 3) & 15;
  const int pg  = bid >> 7;
  const int p   = pg * 8 + xcd;    // 0..31
  const int b   = p >> 1, h = p & 1;
  const int n0  = nt * 64;

  const float* adj = (h == 0 ? adj1 : adj2) + (size_t)b * Nn * Nn;
  const u16* Yb = Y + ((size_t)(b * 256 + h * 128)) * Nn;  // [128][1024] bf16

  const int w = t >> 6, l = t & 63;
  const int wm = w >> 1, wn = w & 1;          // 2 m x 2 n waves
  const int lr = l & 15, lg = l >> 4;

  // ---- A staging: 512 chunks of 16 B; thread does chunks t and t+256.
  // chunk c -> row c>>2, col (c&3) ^ swizzle(row). (t+256 -> row+64, same
  // swizzle since (row+64)>>1 ≡ row>>1 mod 4.)
  const int a_r = t >> 2, a_c = t & 3;
  const int a_cg = a_c ^ ((a_r >> 1) & 3);
  const u16* a_src = Yb + (size_t)a_r * Nn + a_cg * 8;    // + tt*BK at use
  const int a_dst0 = (w * 64) * 8;                         // chunks w*64..+63
  const int a_dst1 = (256 + w * 64) * 8;                   // chunks 256+w*64..

  // ---- B pass1: row-wise contiguous reads (rows b1r, b1r+16; 16 float4/row)
  const int b1r = t >> 4, b1c4 = t & 15;
  const float* bsrc0 = adj + (size_t)b1r * Nn + n0 + 4 * b1c4;
  const float* bsrc1 = adj + (size_t)(b1r + 16) * Nn + n0 + 4 * b1c4;

  // ---- B pass2: thread owns col n = t>>2 (0..63), k-quad kq = t&3 ----
  const int p2n = t >> 2, p2kq = t & 3;

  f32x4 acc[4][2] = {};

  auto ISSUE_A = [&](int tt) {
    gload_lds16(a_src + tt * BK, (void*)(&As[tt & 3][0] + a_dst0));
    gload_lds16(a_src + (size_t)64 * Nn + tt * BK, (void*)(&As[tt & 3][0] + a_dst1));
  };
  auto LOAD_B = [&](int tt, float4 (&v)[2]) {
    v[0] = *reinterpret_cast<const float4*>(bsrc0 + (size_t)tt * BK * Nn);
    v[1] = *reinterpret_cast<const float4*>(bsrc1 + (size_t)tt * BK * Nn);
  };
  auto PASS1 = [&](int tt, const float4 (&v)[2]) {
#pragma unroll
    for (int i = 0; i < 2; ++i) {
      union { uint2 q; u16 s[4]; } ub;
      ub.s[0] = f2bf(v[i].x); ub.s[1] = f2bf(v[i].y);
      ub.s[2] = f2bf(v[i].z); ub.s[3] = f2bf(v[i].w);
      *reinterpret_cast<uint2*>(&Bb[tt & 1][0] + (i * 16 + b1r) * SB1 + 4 * b1c4) = ub.q;
    }
  };
  auto PASS2 = [&](int tt) {
    const u16* src = &Bb[tt & 1][0];
    union { uint4 q; u16 s[8]; } up;
#pragma unroll
    for (int j2 = 0; j2 < 8; ++j2)
      up.s[j2] = src[(p2kq * 8 + j2) * SB1 + p2n];
    *reinterpret_cast<uint4*>(&Bs2[tt & 1][0] + p2n * SB2 + p2kq * 8) = up.q;
  };
  auto COMPUTE = [&](int tt) {
    const u16* Ab = &As[tt & 3][0];
    const u16* Bbf = &Bs2[tt & 1][0];
    bf16x8 af[4], bfr[2];
#pragma unroll
    for (int mi = 0; mi < 4; ++mi) {
      const int rr = wm * 64 + mi * 16 + lr;
      const int cw = lg ^ ((rr >> 1) & 3);
      af[mi] = ld_frag16(Ab + rr * BK + cw * 8);
    }
#pragma unroll
    for (int ni = 0; ni < 2; ++ni) {
      const int cc = wn * 32 + ni * 16 + lr;
      bfr[ni] = ld_frag16(Bbf + cc * SB2 + lg * 8);
    }
#pragma unroll
    for (int mi = 0; mi < 4; ++mi)
#pragma unroll
      for (int ni = 0; ni < 2; ++ni)
        acc[mi][ni] = __builtin_amdgcn_mfma_f32_16x16x32_bf16(
            af[mi], bfr[ni], acc[mi][ni], 0, 0, 0);
  };

  float4 regA[2], regB[2];   // even-tile loads -> regA, odd -> regB

  // ---- prologue: tiles 0,1 issued; Bb[0] published ----
  ISSUE_A(0); LOAD_B(0, regA);
  ISSUE_A(1); LOAD_B(1, regB);
  PASS1(0, regA);            // vmcnt wait on regA also proves As[0] landed
  bar_lds();

  // ---- main loop (NT=32), unrolled x2 for static regA/regB ping-pong ----
  for (int jj = 0; jj < NT / 2; ++jj) {
    const int j0 = 2 * jj;
    if (j0 + 2 < NT) { ISSUE_A(j0 + 2); LOAD_B(j0 + 2, regA); }
    PASS1(j0 + 1, regB);     // counted vmcnt: newer ops stay in flight
    PASS2(j0);
    bar_lds();
    COMPUTE(j0);

    const int j1 = j0 + 1;
    if (j1 + 2 < NT) { ISSUE_A(j1 + 2); LOAD_B(j1 + 2, regB); }
    if (j1 + 1 < NT) PASS1(j1 + 1, regA);
    PASS2(j1);
    bar_lds();
    COMPUTE(j1);
  }

  // ---- epilogue: bias + relu, fp32 store ----
#pragma unroll
  for (int mi = 0; mi < 4; ++mi) {
#pragma unroll
    for (int rr = 0; rr < 4; ++rr) {
      const int go = h * 128 + wm * 64 + mi * 16 + lg * 4 + rr;
      const float bi = bias[go];
      float* orow = out + ((size_t)(b * 256 + go)) * Nn + n0;
#pragma unroll
      for (int ni = 0; ni < 2; ++ni) {
        const int col = wn * 32 + ni * 16 + lr;
        orow[col] = fmaxf(acc[mi][ni][rr] + bi, 0.f);
      }
    }
  }
}

extern "C" void kernel_launch(void* const* d_in, const int* in_sizes, int n_in,
                              void* d_out, int out_size, void* d_ws, size_t ws_size,
                              hipStream_t stream) {
  const float* x    = (const float*)d_in[0];
  const float* adj1 = (const float*)d_in[1];
  const float* adj2 = (const float*)d_in[2];
  const float* wgt  = (const float*)d_in[3];
  const float* bias = (const float*)d_in[4];
  float* out = (float*)d_out;
  u16* Y = (u16*)d_ws;   // 16*256*1024 bf16 = 8.4 MB

  dim3 g1(16, 2, 16);
  gemm1<<<g1, dim3(256), 0, stream>>>(x, wgt, Y);
  gemm2<<<dim3(512), dim3(256), 0, stream>>>(adj1, adj2, Y, bias, out);
}